// Round 1
// baseline (197.677 us; speedup 1.0000x reference)
//
#include <hip/hip_runtime.h>
#include <stdint.h>
#include <math.h>

#define TPB 1024
#define NBINS 2048
#define CAND_MAX 2048

// monotonic float -> uint key (ascending key == ascending float)
__device__ __forceinline__ unsigned fkey(float f) {
    unsigned u = __float_as_uint(f);
    return (u & 0x80000000u) ? ~u : (u | 0x80000000u);
}
__device__ __forceinline__ float funkey(unsigned k) {
    unsigned u = (k & 0x80000000u) ? (k ^ 0x80000000u) : ~k;
    return __uint_as_float(u);
}

__global__ __launch_bounds__(TPB)
void sampler_kernel(const float* __restrict__ logits,
                    const float* __restrict__ temps,
                    const int* __restrict__ top_ks,
                    const float* __restrict__ top_ps,
                    const float* __restrict__ min_ps,
                    const float* __restrict__ uvec,
                    float* __restrict__ out_tok,
                    float* __restrict__ out_probs,
                    int V)
{
    const int b   = blockIdx.x;
    const int tid = threadIdx.x;
    const float* __restrict__ row = logits + (size_t)b * V;
    const float invT  = 1.0f / temps[b];
    int K = top_ks[b];
    if (K < 1) K = 1;
    if (K > 1024) K = 1024;
    const float top_p = top_ps[b];
    const float min_p = min_ps[b];
    const float uval  = uvec[b];

    __shared__ unsigned sh_hist[NBINS];
    __shared__ unsigned long long sh_cand[CAND_MAX];
    __shared__ float sh_p[TPB];
    __shared__ float sh_c[TPB];
    __shared__ float sh_m[TPB];
    __shared__ float sh_s[TPB];
    __shared__ unsigned sh_cnt;
    __shared__ int sh_b1, sh_b2;
    __shared__ unsigned sh_cab;
    __shared__ int sh_np, sh_nf;

    const int V4 = V >> 2;
    const float4* __restrict__ row4 = (const float4*)row;

    // ---------- pass 1: online softmax + level-1 histogram (key bits 31:21) ----------
    for (int i = tid; i < NBINS; i += TPB) sh_hist[i] = 0;
    if (tid == 0) sh_cnt = 0;
    __syncthreads();

    float m = -INFINITY, s = 0.0f;
    for (int i = tid; i < V4; i += TPB) {
        float4 v = row4[i];
        float vv[4] = {v.x, v.y, v.z, v.w};
        #pragma unroll
        for (int j = 0; j < 4; ++j) {
            float lv = vv[j];
            atomicAdd(&sh_hist[fkey(lv) >> 21], 1u);
            float x = lv * invT;
            if (x > m) { s = s * expf(m - x) + 1.0f; m = x; }
            else       { s += expf(x - m); }
        }
    }
    for (int i = (V4 << 2) + tid; i < V; i += TPB) {
        float lv = row[i];
        atomicAdd(&sh_hist[fkey(lv) >> 21], 1u);
        float x = lv * invT;
        if (x > m) { s = s * expf(m - x) + 1.0f; m = x; }
        else       { s += expf(x - m); }
    }
    sh_m[tid] = m; sh_s[tid] = s;
    __syncthreads();
    for (int d = TPB >> 1; d > 0; d >>= 1) {
        if (tid < d) {
            float m1 = sh_m[tid], s1 = sh_s[tid];
            float m2 = sh_m[tid + d], s2 = sh_s[tid + d];
            float mm = fmaxf(m1, m2);
            float t1 = (s1 > 0.0f) ? s1 * expf(m1 - mm) : 0.0f;
            float t2 = (s2 > 0.0f) ? s2 * expf(m2 - mm) : 0.0f;
            sh_s[tid] = t1 + t2;
            sh_m[tid] = mm;
        }
        __syncthreads();
    }
    const float M = sh_m[0];
    const float Z = sh_s[0];
    const unsigned Ku = (unsigned)K;

    // suffix-sum histogram in place: S[i] = #keys with bin >= i
    for (int d = 1; d < NBINS; d <<= 1) {
        unsigned a0 = (tid + d < NBINS) ? sh_hist[tid + d] : 0u;
        int e1 = tid + TPB;
        unsigned a1 = (e1 + d < NBINS) ? sh_hist[e1 + d] : 0u;
        __syncthreads();
        sh_hist[tid] += a0;
        sh_hist[e1]  += a1;
        __syncthreads();
    }
    // boundary: largest bin with S >= K (unique: S nonincreasing)
    for (int e = tid; e < NBINS; e += TPB) {
        unsigned Se = sh_hist[e];
        unsigned Sn = (e + 1 < NBINS) ? sh_hist[e + 1] : 0u;
        if (Se >= Ku && (e + 1 >= NBINS || Sn < Ku)) { sh_b1 = e; sh_cab = Sn; }
    }
    __syncthreads();
    const int b1 = sh_b1;
    const unsigned cab = sh_cab;   // count strictly above bin b1
    __syncthreads();

    // ---------- pass 2: level-2 histogram (key bits 20:10) inside bin b1 ----------
    for (int i = tid; i < NBINS; i += TPB) sh_hist[i] = 0;
    __syncthreads();
    for (int i = tid; i < V4; i += TPB) {
        float4 v = row4[i];
        float vv[4] = {v.x, v.y, v.z, v.w};
        #pragma unroll
        for (int j = 0; j < 4; ++j) {
            unsigned k = fkey(vv[j]);
            if ((int)(k >> 21) == b1) atomicAdd(&sh_hist[(k >> 10) & (NBINS - 1)], 1u);
        }
    }
    for (int i = (V4 << 2) + tid; i < V; i += TPB) {
        unsigned k = fkey(row[i]);
        if ((int)(k >> 21) == b1) atomicAdd(&sh_hist[(k >> 10) & (NBINS - 1)], 1u);
    }
    __syncthreads();
    for (int d = 1; d < NBINS; d <<= 1) {
        unsigned a0 = (tid + d < NBINS) ? sh_hist[tid + d] : 0u;
        int e1 = tid + TPB;
        unsigned a1 = (e1 + d < NBINS) ? sh_hist[e1 + d] : 0u;
        __syncthreads();
        sh_hist[tid] += a0;
        sh_hist[e1]  += a1;
        __syncthreads();
    }
    for (int e = tid; e < NBINS; e += TPB) {
        unsigned Se = cab + sh_hist[e];
        unsigned Sn = cab + ((e + 1 < NBINS) ? sh_hist[e + 1] : 0u);
        if (Se >= Ku && (e + 1 >= NBINS || Sn < Ku)) sh_b2 = e;
    }
    __syncthreads();
    const unsigned Tkey = ((unsigned)b1 << 21) | ((unsigned)sh_b2 << 10);

    // ---------- pass 3: gather candidates (key >= Tkey), count in [K, K+eps] ----------
    for (int i = tid; i < V4; i += TPB) {
        float4 v = row4[i];
        float vv[4] = {v.x, v.y, v.z, v.w};
        int base = i << 2;
        #pragma unroll
        for (int j = 0; j < 4; ++j) {
            unsigned k = fkey(vv[j]);
            if (k >= Tkey) {
                unsigned pos = atomicAdd(&sh_cnt, 1u);
                if (pos < CAND_MAX)
                    sh_cand[pos] = ((unsigned long long)k << 32) |
                                   (unsigned long long)(~(unsigned)(base + j));
            }
        }
    }
    for (int i = (V4 << 2) + tid; i < V; i += TPB) {
        unsigned k = fkey(row[i]);
        if (k >= Tkey) {
            unsigned pos = atomicAdd(&sh_cnt, 1u);
            if (pos < CAND_MAX)
                sh_cand[pos] = ((unsigned long long)k << 32) |
                               (unsigned long long)(~(unsigned)i);
        }
    }
    __syncthreads();
    int count = (sh_cnt < (unsigned)CAND_MAX) ? (int)sh_cnt : CAND_MAX;
    if (K > count) K = count;

    // ---------- bitonic sort descending by (key desc, idx asc) ----------
    int n_sort = 1;
    while (n_sort < count) n_sort <<= 1;
    for (int i = tid; i < n_sort; i += TPB)
        if (i >= count) sh_cand[i] = 0ull;   // pads sort to the end (descending)
    __syncthreads();
    for (int kk = 2; kk <= n_sort; kk <<= 1) {
        for (int j = kk >> 1; j > 0; j >>= 1) {
            for (int i = tid; i < n_sort; i += TPB) {
                int ixj = i ^ j;
                if (ixj > i) {
                    unsigned long long a = sh_cand[i];
                    unsigned long long c = sh_cand[ixj];
                    bool up = (i & kk) == 0;
                    if (up ? (a < c) : (a > c)) { sh_cand[i] = c; sh_cand[ixj] = a; }
                }
            }
            __syncthreads();
        }
    }

    // ---------- probs for top-K prefix, cumsum, masks ----------
    float pv = 0.0f;
    if (tid < K) {
        unsigned k = (unsigned)(sh_cand[tid] >> 32);
        float x = funkey(k) * invT;
        pv = expf(x - M) / Z;
    }
    sh_p[tid] = pv;
    sh_c[tid] = pv;
    __syncthreads();
    for (int d = 1; d < TPB; d <<= 1) {
        float add = (tid >= d) ? sh_c[tid - d] : 0.0f;
        __syncthreads();
        sh_c[tid] += add;
        __syncthreads();
    }

    if (tid == 0) sh_np = K;
    __syncthreads();
    if (tid < K) {
        float excl = sh_c[tid] - sh_p[tid];     // exclusive cumsum (cumsum BEFORE masking)
        if (excl > top_p) atomicMin(&sh_np, tid);
    }
    __syncthreads();
    int n1 = sh_np;                              // survivors of top-k & top-p
    float thr = sh_p[0] * min_p;                 // rank-0 always survives both masks
    if (tid == 0) sh_nf = n1;
    __syncthreads();
    if (tid < n1 && sh_p[tid] < thr) atomicMin(&sh_nf, tid);
    __syncthreads();
    int nf = sh_nf;                              // final survivor count, >= 1
    float total = sh_c[nf - 1];

    // ---------- inverse-CDF sample ----------
    int pred = (tid < nf) && ((sh_c[tid] / total) < uval);
    int rank = __syncthreads_count(pred);
    if (rank > nf - 1) rank = nf - 1;
    if (rank < 0) rank = 0;
    if (tid == 0) {
        unsigned idx = ~(unsigned)(sh_cand[rank] & 0xFFFFFFFFull);
        out_tok[b] = (float)idx;                 // ids < 2^24: exact in f32
    }

    // ---------- zero the row, scatter renormalized survivor probs ----------
    float4* orow4 = (float4*)(out_probs + (size_t)b * V);
    float4 z4; z4.x = z4.y = z4.z = z4.w = 0.0f;
    for (int i = tid; i < V4; i += TPB) orow4[i] = z4;
    for (int i = (V4 << 2) + tid; i < V; i += TPB) out_probs[(size_t)b * V + i] = 0.0f;
    __syncthreads();
    if (tid < nf) {
        unsigned idx = ~(unsigned)(sh_cand[tid] & 0xFFFFFFFFull);
        out_probs[(size_t)b * V + idx] = sh_p[tid] / total;
    }
}

extern "C" void kernel_launch(void* const* d_in, const int* in_sizes, int n_in,
                              void* d_out, int out_size, void* d_ws, size_t ws_size,
                              hipStream_t stream) {
    const float* logits = (const float*)d_in[0];
    const float* temps  = (const float*)d_in[1];
    const int*   top_ks = (const int*)d_in[2];
    const float* top_ps = (const float*)d_in[3];
    const float* min_ps = (const float*)d_in[4];
    const float* u      = (const float*)d_in[5];
    int B = in_sizes[1];
    int V = in_sizes[0] / B;
    float* out = (float*)d_out;
    sampler_kernel<<<dim3(B), dim3(TPB), 0, stream>>>(
        logits, temps, top_ks, top_ps, min_ps, u, out, out + B, V);
}